// Round 1
// baseline (55.132 us; speedup 1.0000x reference)
//
#include <hip/hip_runtime.h>

// MaskPatches: out[c,t,h,w] = frames[c,t,h,w] * (masked(t, h/14, w/14) ? 0 : 1)
// masked(t, ph, pw) iff exists idx in mask_indices[t,:] with idx%16==ph, idx/16==pw.
//
// frames: [3,256,224,224] f32; mask_indices: [256,128] i32; out same shape as frames.
// Memory-bound: ~308 MB HBM traffic -> ~49 us floor at 6.3 TB/s.

constexpr int T_N    = 256;
constexpr int C_N    = 3;
constexpr int H_N    = 224;
constexpr int W_N    = 224;
constexpr int SIDE   = 16;              // patch grid side (224/14)
constexpr int PATCH  = 14;
constexpr int M_N    = 128;             // masked patches per frame
constexpr int F4_ROW = W_N / 4;         // 56 float4 per pixel row
constexpr int F4_BAND = PATCH * F4_ROW; // 784 float4 per 14-row band
constexpr int F4_PLANE = H_N * W_N / 4; // 12544 float4 per (c,t) plane

__global__ __launch_bounds__(256)
void MaskPatches_74818330296837_kernel(const float4* __restrict__ frames,
                                       const int*    __restrict__ midx,
                                       float4*       __restrict__ out)
{
    __shared__ float mrow[SIDE];

    const int bid = blockIdx.x;          // = (c*T + t)*16 + ph
    const int ph  = bid & 15;            // patch-grid row handled by this block
    const int ct  = bid >> 4;            // c*T + t   (T == 256)
    const int t   = ct & 255;

    const int tid = threadIdx.x;

    // Build the 16-entry mask row for this ph.
    if (tid < SIDE) mrow[tid] = 1.0f;
    __syncthreads();                     // order init before masking writes
    if (tid < M_N) {
        const int idx = midx[t * M_N + tid];   // in [0, 256)
        // reference: h_idx = idx % 16 (row), w_idx = idx / 16 (col)
        if ((idx & 15) == ph) mrow[idx >> 4] = 0.0f;
    }
    __syncthreads();

    // Band base in float4 units: plane ct, rows [ph*14, ph*14+14)
    const long long base = (long long)ct * F4_PLANE + (long long)ph * F4_BAND;

    for (int i = tid; i < F4_BAND; i += 256) {
        const int col4 = i % F4_ROW;     // float4 column within the row
        const int w    = col4 * 4;
        float4 v = frames[base + i];
        v.x *= mrow[(w    ) / PATCH];
        v.y *= mrow[(w + 1) / PATCH];
        v.z *= mrow[(w + 2) / PATCH];
        v.w *= mrow[(w + 3) / PATCH];
        out[base + i] = v;
    }
}

extern "C" void kernel_launch(void* const* d_in, const int* in_sizes, int n_in,
                              void* d_out, int out_size, void* d_ws, size_t ws_size,
                              hipStream_t stream) {
    const float4* frames = (const float4*)d_in[0];
    const int*    midx   = (const int*)d_in[1];
    float4*       out    = (float4*)d_out;

    const int grid = C_N * T_N * SIDE;   // 12288 blocks
    MaskPatches_74818330296837_kernel<<<grid, 256, 0, stream>>>(frames, midx, out);
}

// Round 3
// 54.509 us; speedup vs baseline: 1.0114x; 1.0114x over previous
//
#include <hip/hip_runtime.h>

// MaskPatches: out[c,t,h,w] = frames[c,t,h,w] * (masked(t, h/14, w/14) ? 0 : 1)
// masked(t,ph,pw) iff exists idx in mask_indices[t,:]: idx%16==ph, idx/16==pw.
//
// frames: [3,256,224,224] f32; mask_indices: [256,128] i32.
// Pure streaming multiply: ~308 MB HBM traffic -> ~49 us at 6.3 TB/s copy ceiling.
//
// Structure: 1 block per (t, ph) = 4096 blocks x 256 threads, covering the
// 14-row band of ALL 3 channels (2352 float4 / block). No LDS, no barriers:
// each wave loads all 128 indices itself (2/lane) and OR-reduces a 16-bit
// patch-row mask via shfl_xor. Index loads issue first, then all frame loads,
// so every latency overlaps in one in-flight window. Non-temporal load/store
// (no reuse, keep L2 clean). NOTE: nontemporal builtins need a clang
// ext_vector_type, not HIP's float4 struct.

typedef float f32x4 __attribute__((ext_vector_type(4)));

constexpr int T_N     = 256;
constexpr int H_N     = 224;
constexpr int W_N     = 224;
constexpr int SIDE    = 16;               // patch grid side
constexpr int PATCH   = 14;
constexpr int M_N     = 128;              // masked patches per frame
constexpr int F4_ROW  = W_N / 4;          // 56 float4 per pixel row
constexpr int F4_BAND = PATCH * F4_ROW;   // 784 float4 per band
constexpr int F4_PLANE = H_N * W_N / 4;   // 12544 float4 per (c,t) plane
constexpr long long F4_CHAN = (long long)T_N * F4_PLANE; // channel stride in f4

__global__ __launch_bounds__(256)
void MaskPatches_74818330296837_kernel(const f32x4* __restrict__ frames,
                                       const int*   __restrict__ midx,
                                       f32x4*       __restrict__ out)
{
    const int bid  = blockIdx.x;
    const int ph   = bid & 15;            // patch-grid row for this block
    const int t    = bid >> 4;
    const int tid  = threadIdx.x;
    const int lane = tid & 63;

    // 1) index loads first (oldest in vmcnt queue -> cheapest to wait on)
    const int* row = midx + t * M_N;
    const int i0 = row[lane];
    const int i1 = row[lane + 64];

    // 2) all frame loads for the 3-channel band (10-12 float4 / lane)
    const long long base0 = (long long)t * F4_PLANE + (long long)ph * F4_BAND;
    const bool tail = tid < (F4_BAND - 3 * 256);   // 16 threads handle i=768..783
    f32x4 v[3][4];
    #pragma unroll
    for (int c = 0; c < 3; ++c) {
        const f32x4* p = frames + base0 + c * F4_CHAN;
        v[c][0] = __builtin_nontemporal_load(p + tid);
        v[c][1] = __builtin_nontemporal_load(p + tid + 256);
        v[c][2] = __builtin_nontemporal_load(p + tid + 512);
        v[c][3] = tail ? __builtin_nontemporal_load(p + tid + 768)
                       : (f32x4)(0.f);
    }

    // 3) per-wave 16-bit row mask: bit pw set iff patch (ph,pw) is masked
    unsigned bits = 0;
    if ((i0 & 15) == ph) bits |= 1u << (i0 >> 4);
    if ((i1 & 15) == ph) bits |= 1u << (i1 >> 4);
    #pragma unroll
    for (int s = 1; s < 64; s <<= 1)
        bits |= (unsigned)__shfl_xor((int)bits, s, 64);

    // 4) per-lane multipliers — identical across channels, compute once
    f32x4 m[4];
    #pragma unroll
    for (int k = 0; k < 4; ++k) {
        const unsigned i = (unsigned)(tid + k * 256);
        const unsigned w = (i % F4_ROW) * 4;
        #pragma unroll
        for (int j = 0; j < 4; ++j)
            m[k][j] = ((bits >> ((w + j) / PATCH)) & 1u) ? 0.0f : 1.0f;
    }

    // 5) multiply + non-temporal store
    #pragma unroll
    for (int c = 0; c < 3; ++c) {
        f32x4* q = out + base0 + c * F4_CHAN;
        #pragma unroll
        for (int k = 0; k < 3; ++k)
            __builtin_nontemporal_store(v[c][k] * m[k], q + tid + k * 256);
        if (tail)
            __builtin_nontemporal_store(v[c][3] * m[3], q + tid + 768);
    }
}

extern "C" void kernel_launch(void* const* d_in, const int* in_sizes, int n_in,
                              void* d_out, int out_size, void* d_ws, size_t ws_size,
                              hipStream_t stream) {
    const f32x4* frames = (const f32x4*)d_in[0];
    const int*   midx   = (const int*)d_in[1];
    f32x4*       out    = (f32x4*)d_out;

    const int grid = T_N * SIDE;          // 4096 blocks: one per (t, ph)
    MaskPatches_74818330296837_kernel<<<grid, 256, 0, stream>>>(frames, midx, out);
}

// Round 4
// 53.974 us; speedup vs baseline: 1.0214x; 1.0099x over previous
//
#include <hip/hip_runtime.h>

// MaskPatches: out[c,t,h,w] = frames[c,t,h,w] * (masked(t, h/14, w/14) ? 0 : 1)
// masked(t,ph,pw) iff exists idx in mask_indices[t,:]: idx%16==ph, idx/16==pw.
//
// frames: [3,256,224,224] f32; mask_indices: [256,128] i32.
// Pure streaming multiply: ~308 MB HBM traffic -> 49.0 us floor at the
// measured 6.29 TB/s float4-copy ceiling (m13).
//
// R4 A/B: identical to R3 except ALL nontemporal hints removed (single
// variable). R3 (with NT) = 54.51 us. If NT was hurting L2 write-combining
// or read-line handling, this recovers 2-4 us; if unchanged, we are at the
// mixed read+write stream ceiling for this chip.
//
// Structure: 1 block per (t, ph) = 4096 blocks x 256 threads, covering the
// 14-row band of ALL 3 channels (2352 float4 / block). No LDS, no barriers:
// each wave loads all 128 indices itself (2/lane) and OR-reduces a 16-bit
// patch-row mask via shfl_xor.

typedef float f32x4 __attribute__((ext_vector_type(4)));

constexpr int T_N     = 256;
constexpr int H_N     = 224;
constexpr int W_N     = 224;
constexpr int SIDE    = 16;               // patch grid side
constexpr int PATCH   = 14;
constexpr int M_N     = 128;              // masked patches per frame
constexpr int F4_ROW  = W_N / 4;          // 56 float4 per pixel row
constexpr int F4_BAND = PATCH * F4_ROW;   // 784 float4 per band
constexpr int F4_PLANE = H_N * W_N / 4;   // 12544 float4 per (c,t) plane
constexpr long long F4_CHAN = (long long)T_N * F4_PLANE; // channel stride in f4

__global__ __launch_bounds__(256)
void MaskPatches_74818330296837_kernel(const f32x4* __restrict__ frames,
                                       const int*   __restrict__ midx,
                                       f32x4*       __restrict__ out)
{
    const int bid  = blockIdx.x;
    const int ph   = bid & 15;            // patch-grid row for this block
    const int t    = bid >> 4;
    const int tid  = threadIdx.x;
    const int lane = tid & 63;

    // 1) index loads first (oldest in vmcnt queue -> cheapest to wait on)
    const int* row = midx + t * M_N;
    const int i0 = row[lane];
    const int i1 = row[lane + 64];

    // 2) all frame loads for the 3-channel band (10-12 float4 / lane)
    const long long base0 = (long long)t * F4_PLANE + (long long)ph * F4_BAND;
    const bool tail = tid < (F4_BAND - 3 * 256);   // 16 threads handle i=768..783
    f32x4 v[3][4];
    #pragma unroll
    for (int c = 0; c < 3; ++c) {
        const f32x4* p = frames + base0 + c * F4_CHAN;
        v[c][0] = p[tid];
        v[c][1] = p[tid + 256];
        v[c][2] = p[tid + 512];
        v[c][3] = tail ? p[tid + 768] : (f32x4)(0.f);
    }

    // 3) per-wave 16-bit row mask: bit pw set iff patch (ph,pw) is masked
    unsigned bits = 0;
    if ((i0 & 15) == ph) bits |= 1u << (i0 >> 4);
    if ((i1 & 15) == ph) bits |= 1u << (i1 >> 4);
    #pragma unroll
    for (int s = 1; s < 64; s <<= 1)
        bits |= (unsigned)__shfl_xor((int)bits, s, 64);

    // 4) per-lane multipliers — identical across channels, compute once
    f32x4 m[4];
    #pragma unroll
    for (int k = 0; k < 4; ++k) {
        const unsigned i = (unsigned)(tid + k * 256);
        const unsigned w = (i % F4_ROW) * 4;
        #pragma unroll
        for (int j = 0; j < 4; ++j)
            m[k][j] = ((bits >> ((w + j) / PATCH)) & 1u) ? 0.0f : 1.0f;
    }

    // 5) multiply + store
    #pragma unroll
    for (int c = 0; c < 3; ++c) {
        f32x4* q = out + base0 + c * F4_CHAN;
        #pragma unroll
        for (int k = 0; k < 3; ++k)
            q[tid + k * 256] = v[c][k] * m[k];
        if (tail)
            q[tid + 768] = v[c][3] * m[3];
    }
}

extern "C" void kernel_launch(void* const* d_in, const int* in_sizes, int n_in,
                              void* d_out, int out_size, void* d_ws, size_t ws_size,
                              hipStream_t stream) {
    const f32x4* frames = (const f32x4*)d_in[0];
    const int*   midx   = (const int*)d_in[1];
    f32x4*       out    = (f32x4*)d_out;

    const int grid = T_N * SIDE;          // 4096 blocks: one per (t, ph)
    MaskPatches_74818330296837_kernel<<<grid, 256, 0, stream>>>(frames, midx, out);
}

// Round 5
// 53.404 us; speedup vs baseline: 1.0323x; 1.0107x over previous
//
#include <hip/hip_runtime.h>

// MaskPatches: out[c,t,h,w] = frames[c,t,h,w] * (masked(t, h/14, w/14) ? 0 : 1)
// masked(t,ph,pw) iff exists idx in mask_indices[t,:]: idx%16==ph, idx/16==pw.
//
// frames: [3,256,224,224] f32; mask_indices: [256,128] i32.
// Streaming multiply. Naive traffic: 154 MB read + 154 MB write -> 49.0 us
// floor at the measured 6.29 TB/s copy ceiling. R4 (no skip) = 53.97 us.
//
// R5: skip frame LOADS whose entire float4 lies in masked patches (output is
// zero there; writes still required). P(lane skippable) ~ 0.155; at 64B HBM
// line granularity ~14% of read lines become untouched -> ~22 MB less fetch.
// Mask is computed before loads now (per-wave shfl_xor OR-reduce, no LDS).

typedef float f32x4 __attribute__((ext_vector_type(4)));

constexpr int T_N     = 256;
constexpr int H_N     = 224;
constexpr int W_N     = 224;
constexpr int SIDE    = 16;               // patch grid side
constexpr int PATCH   = 14;
constexpr int M_N     = 128;              // masked patches per frame
constexpr int F4_ROW  = W_N / 4;          // 56 float4 per pixel row
constexpr int F4_BAND = PATCH * F4_ROW;   // 784 float4 per band
constexpr int F4_PLANE = H_N * W_N / 4;   // 12544 float4 per (c,t) plane
constexpr long long F4_CHAN = (long long)T_N * F4_PLANE; // channel stride in f4

__global__ __launch_bounds__(256)
void MaskPatches_74818330296837_kernel(const f32x4* __restrict__ frames,
                                       const int*   __restrict__ midx,
                                       f32x4*       __restrict__ out)
{
    const int bid  = blockIdx.x;
    const int ph   = bid & 15;            // patch-grid row for this block
    const int t    = bid >> 4;
    const int tid  = threadIdx.x;
    const int lane = tid & 63;

    // 1) index loads + per-wave 16-bit row mask (bit pw = patch (ph,pw) masked)
    const int* row = midx + t * M_N;
    const int i0 = row[lane];
    const int i1 = row[lane + 64];
    unsigned bits = 0;
    if ((i0 & 15) == ph) bits |= 1u << (i0 >> 4);
    if ((i1 & 15) == ph) bits |= 1u << (i1 >> 4);
    #pragma unroll
    for (int s = 1; s < 64; s <<= 1)
        bits |= (unsigned)__shfl_xor((int)bits, s, 64);

    // 2) per-lane multipliers + skip flags (all-4-pixels-masked -> skip load)
    f32x4 m[4];
    bool  skip[4];
    #pragma unroll
    for (int k = 0; k < 4; ++k) {
        const unsigned i = (unsigned)(tid + k * 256);
        const unsigned w = (i % F4_ROW) * 4;
        #pragma unroll
        for (int j = 0; j < 4; ++j)
            m[k][j] = ((bits >> ((w + j) / PATCH)) & 1u) ? 0.0f : 1.0f;
        const unsigned pa = w / PATCH, pb = (w + 3) / PATCH;
        skip[k] = (((bits >> pa) & (bits >> pb)) & 1u) != 0u;
    }

    // 3) predicated frame loads for the 3-channel band
    const long long base0 = (long long)t * F4_PLANE + (long long)ph * F4_BAND;
    const bool tail = tid < (F4_BAND - 3 * 256);   // 16 threads handle i=768..783
    f32x4 v[3][4];
    #pragma unroll
    for (int c = 0; c < 3; ++c) {
        const f32x4* p = frames + base0 + c * F4_CHAN;
        v[c][0] = skip[0] ? (f32x4)(0.f) : p[tid];
        v[c][1] = skip[1] ? (f32x4)(0.f) : p[tid + 256];
        v[c][2] = skip[2] ? (f32x4)(0.f) : p[tid + 512];
        v[c][3] = (tail && !skip[3]) ? p[tid + 768] : (f32x4)(0.f);
    }

    // 4) multiply + store (stores unconditional: zeros must land)
    #pragma unroll
    for (int c = 0; c < 3; ++c) {
        f32x4* q = out + base0 + c * F4_CHAN;
        #pragma unroll
        for (int k = 0; k < 3; ++k)
            q[tid + k * 256] = v[c][k] * m[k];
        if (tail)
            q[tid + 768] = v[c][3] * m[3];
    }
}

extern "C" void kernel_launch(void* const* d_in, const int* in_sizes, int n_in,
                              void* d_out, int out_size, void* d_ws, size_t ws_size,
                              hipStream_t stream) {
    const f32x4* frames = (const f32x4*)d_in[0];
    const int*   midx   = (const int*)d_in[1];
    f32x4*       out    = (f32x4*)d_out;

    const int grid = T_N * SIDE;          // 4096 blocks: one per (t, ph)
    MaskPatches_74818330296837_kernel<<<grid, 256, 0, stream>>>(frames, midx, out);
}

// Round 6
// 47.820 us; speedup vs baseline: 1.1529x; 1.1168x over previous
//
#include <hip/hip_runtime.h>

// MaskPatches: out[c,t,h,w] = frames[c,t,h,w] * (masked(t, h/14, w/14) ? 0 : 1)
// masked(t,ph,pw) iff exists idx in mask_indices[t,:]: idx%16==ph, idx/16==pw.
//
// frames: [3,256,224,224] f32; mask_indices: [256,128] i32.
// R5 profile insight: input (154 MB) partially L3-resident across replays
// (FETCH=71.6 MB < 154 MB), but the 154 MB/replay write stream allocates in
// L3 and evicts it. R6 single variable: NON-TEMPORAL STORES ONLY (loads stay
// temporal). Write stream no-allocates -> input stays L3-resident -> HBM
// carries mostly writes. R3 tested NT-both (neutral: NT loads canceled the
// store win). R4 = no NT = 53.97 us; R5 (+load skip) = 53.40 us.

typedef float f32x4 __attribute__((ext_vector_type(4)));

constexpr int T_N     = 256;
constexpr int H_N     = 224;
constexpr int W_N     = 224;
constexpr int SIDE    = 16;               // patch grid side
constexpr int PATCH   = 14;
constexpr int M_N     = 128;              // masked patches per frame
constexpr int F4_ROW  = W_N / 4;          // 56 float4 per pixel row
constexpr int F4_BAND = PATCH * F4_ROW;   // 784 float4 per band
constexpr int F4_PLANE = H_N * W_N / 4;   // 12544 float4 per (c,t) plane
constexpr long long F4_CHAN = (long long)T_N * F4_PLANE; // channel stride in f4

__global__ __launch_bounds__(256)
void MaskPatches_74818330296837_kernel(const f32x4* __restrict__ frames,
                                       const int*   __restrict__ midx,
                                       f32x4*       __restrict__ out)
{
    const int bid  = blockIdx.x;
    const int ph   = bid & 15;            // patch-grid row for this block
    const int t    = bid >> 4;
    const int tid  = threadIdx.x;
    const int lane = tid & 63;

    // 1) index loads + per-wave 16-bit row mask (bit pw = patch (ph,pw) masked)
    const int* row = midx + t * M_N;
    const int i0 = row[lane];
    const int i1 = row[lane + 64];
    unsigned bits = 0;
    if ((i0 & 15) == ph) bits |= 1u << (i0 >> 4);
    if ((i1 & 15) == ph) bits |= 1u << (i1 >> 4);
    #pragma unroll
    for (int s = 1; s < 64; s <<= 1)
        bits |= (unsigned)__shfl_xor((int)bits, s, 64);

    // 2) per-lane multipliers + skip flags (all-4-pixels-masked -> skip load)
    f32x4 m[4];
    bool  skip[4];
    #pragma unroll
    for (int k = 0; k < 4; ++k) {
        const unsigned i = (unsigned)(tid + k * 256);
        const unsigned w = (i % F4_ROW) * 4;
        #pragma unroll
        for (int j = 0; j < 4; ++j)
            m[k][j] = ((bits >> ((w + j) / PATCH)) & 1u) ? 0.0f : 1.0f;
        const unsigned pa = w / PATCH, pb = (w + 3) / PATCH;
        skip[k] = (((bits >> pa) & (bits >> pb)) & 1u) != 0u;
    }

    // 3) predicated TEMPORAL frame loads for the 3-channel band
    const long long base0 = (long long)t * F4_PLANE + (long long)ph * F4_BAND;
    const bool tail = tid < (F4_BAND - 3 * 256);   // 16 threads handle i=768..783
    f32x4 v[3][4];
    #pragma unroll
    for (int c = 0; c < 3; ++c) {
        const f32x4* p = frames + base0 + c * F4_CHAN;
        v[c][0] = skip[0] ? (f32x4)(0.f) : p[tid];
        v[c][1] = skip[1] ? (f32x4)(0.f) : p[tid + 256];
        v[c][2] = skip[2] ? (f32x4)(0.f) : p[tid + 512];
        v[c][3] = (tail && !skip[3]) ? p[tid + 768] : (f32x4)(0.f);
    }

    // 4) multiply + NON-TEMPORAL store (don't let writes evict input from L3)
    #pragma unroll
    for (int c = 0; c < 3; ++c) {
        f32x4* q = out + base0 + c * F4_CHAN;
        #pragma unroll
        for (int k = 0; k < 3; ++k)
            __builtin_nontemporal_store(v[c][k] * m[k], q + tid + k * 256);
        if (tail)
            __builtin_nontemporal_store(v[c][3] * m[3], q + tid + 768);
    }
}

extern "C" void kernel_launch(void* const* d_in, const int* in_sizes, int n_in,
                              void* d_out, int out_size, void* d_ws, size_t ws_size,
                              hipStream_t stream) {
    const f32x4* frames = (const f32x4*)d_in[0];
    const int*   midx   = (const int*)d_in[1];
    f32x4*       out    = (f32x4*)d_out;

    const int grid = T_N * SIDE;          // 4096 blocks: one per (t, ph)
    MaskPatches_74818330296837_kernel<<<grid, 256, 0, stream>>>(frames, midx, out);
}